// Round 13
// baseline (201.647 us; speedup 1.0000x reference)
//
#include <hip/hip_runtime.h>
#include <stdint.h>

#define B_    4
#define C_    256
#define W_    4096
#define DQK_  32
#define NT64_ 64      // 64-wide n tiles per batch
#define TSZ_  16384   // shorts per x0t tile (256c x 64n)

typedef short bf16x8 __attribute__((ext_vector_type(8)));
typedef float f32x4  __attribute__((ext_vector_type(4)));

__device__ __forceinline__ float fexp2f(float x){
#if __has_builtin(__builtin_amdgcn_exp2f)
  return __builtin_amdgcn_exp2f(x);
#else
  return exp2f(x);
#endif
}
__device__ __forceinline__ float frcpf(float x){
#if __has_builtin(__builtin_amdgcn_rcpf)
  return __builtin_amdgcn_rcpf(x);
#else
  return 1.0f / x;
#endif
}
// single-instruction packed f32->bf16 (RTNE)
__device__ __forceinline__ uint32_t cvtpk(float a, float b){
  uint32_t r;
  asm("v_cvt_pk_bf16_f32 %0, %1, %2" : "=v"(r) : "v"(a), "v"(b));
  return r;
}
__device__ __forceinline__ unsigned short bf16c(float f){
  return (unsigned short)cvtpk(f, f);
}

// ---------------------------------------------------------------------------
// K1: projections -> qf (MFMA-fragment layout) + kT (row-major) + x0t (bf16,
//     swizzled tiles). Unchanged from R12.
// ---------------------------------------------------------------------------
__global__ __launch_bounds__(512) void sa_prep(
    const float* __restrict__ x0, const float* __restrict__ x1,
    const float* __restrict__ wq, const float* __restrict__ bq,
    const float* __restrict__ wk, const float* __restrict__ bk,
    unsigned short* __restrict__ qf, unsigned short* __restrict__ kT,
    unsigned short* __restrict__ x0t)
{
  const int b     = blockIdx.y;
  const int tid   = threadIdx.x;
  const int lane  = tid & 63;
  const int cq    = tid >> 6;            // 0..7
  const int wloc  = lane & 31;           // n within the 32-block
  const int chalf = lane >> 5;           // 0..1
  const int n0    = blockIdx.x * 32;
  const int n     = n0 + wloc;
  const int c0    = cq * 32 + chalf * 16;
  const size_t bw = (size_t)b * ((size_t)C_ * W_) + n;

  __shared__ union {
    unsigned short xs[256 * 32];   // bf16 stage [c][nloc], 16 KB
    float red[8][32][36];          // cross-wave reduce, 36.9 KB
  } sm;

  float accq[DQK_], acck[DQK_];
  #pragma unroll
  for (int d = 0; d < DQK_; ++d){ accq[d] = 0.f; acck[d] = 0.f; }

  for (int i = 0; i < 16; ++i){
    const int c = c0 + i;
    const size_t off = bw + (size_t)c * W_;
    const float v0 = x0[off];
    const float v1 = x1[off];
    sm.xs[c * 32 + wloc] = bf16c(v0);
    #pragma unroll
    for (int d = 0; d < DQK_; ++d){
      accq[d] = fmaf(wq[d * C_ + c], v0, accq[d]);
      acck[d] = fmaf(wk[d * C_ + c], v1, acck[d]);
    }
  }
  #pragma unroll
  for (int d = 0; d < DQK_; ++d){
    accq[d] += __shfl_xor(accq[d], 32);
    acck[d] += __shfl_xor(acck[d], 32);
  }
  __syncthreads();   // xs complete

  {
    unsigned short* xt = x0t + (size_t)(b * NT64_ + (n0 >> 6)) * TSZ_;
    const int j0 = (n0 >> 3) & 7;
    #pragma unroll
    for (int rep = 0; rep < 2; ++rep){
      const int idx = tid + rep * 512;
      const int row = idx >> 2;
      const int jl  = idx & 3;
      uint4 v = *(const uint4*)&sm.xs[row * 32 + jl * 8];
      *(uint4*)(xt + row * 64 + (((j0 + jl) ^ (row & 7)) << 3)) = v;
    }
  }
  __syncthreads();   // xs free -> red may overwrite

  if (chalf == 0){
    #pragma unroll
    for (int d4 = 0; d4 < 8; ++d4){
      f32x4 t = { accq[d4*4], accq[d4*4+1], accq[d4*4+2], accq[d4*4+3] };
      *(f32x4*)&sm.red[cq][wloc][d4 * 4] = t;
    }
  }
  __syncthreads();
  if (tid < 256){
    const int nl = tid & 31, dg = tid >> 5;
    const int d0 = dg * 4;
    float s[4];
    #pragma unroll
    for (int j = 0; j < 4; ++j){
      float t = bq[d0 + j];
      #pragma unroll
      for (int g = 0; g < 8; ++g) t += sm.red[g][nl][d0 + j];
      s[j] = t;
    }
    uint2 pk; pk.x = cvtpk(s[0], s[1]); pk.y = cvtpk(s[2], s[3]);
    const int ng = n0 + nl;
    const size_t addr = (((size_t)b * 256 + (ng >> 4)) * 64
                         + (ng & 15) + ((dg >> 1) << 4)) * 8 + (dg & 1) * 4;
    *(uint2*)(qf + addr) = pk;
  }
  __syncthreads();

  if (chalf == 0){
    #pragma unroll
    for (int d4 = 0; d4 < 8; ++d4){
      f32x4 t = { acck[d4*4], acck[d4*4+1], acck[d4*4+2], acck[d4*4+3] };
      *(f32x4*)&sm.red[cq][wloc][d4 * 4] = t;
    }
  }
  __syncthreads();
  if (tid < 256){
    const float SCL = 0.0625f * 1.44269504088896340736f; // 1/sqrt(256)*log2(e)
    const int nl = tid & 31, dg = tid >> 5;
    const int d0 = dg * 4;
    float s[4];
    #pragma unroll
    for (int j = 0; j < 4; ++j){
      float t = bk[d0 + j];
      #pragma unroll
      for (int g = 0; g < 8; ++g) t += sm.red[g][nl][d0 + j];
      s[j] = t * SCL;
    }
    uint2 pk; pk.x = cvtpk(s[0], s[1]); pk.y = cvtpk(s[2], s[3]);
    *(uint2*)(kT + ((size_t)b * W_ + n0 + nl) * DQK_ + d0) = pk;
  }
}

// ---------------------------------------------------------------------------
// K2 (pass A): UNNORMALIZED PV + denominators in ONE sweep. No att store in
// the loop (PV is linear in P: normalize at epilogue). Loop carries only
// {q load, STAGE loads, LDS, MFMA} -> __syncthreads drains loads only.
// Epilogue: S cross-wave reduce -> invS-scaled out write; li=-log2(S) to ws.
// grid 512 (XCD-paired per batch), block 512 = 8 waves, LDS ~73KB.
// ---------------------------------------------------------------------------
__global__ __launch_bounds__(512, 4) void sa_pvd(
    const unsigned short* __restrict__ qf, const unsigned short* __restrict__ kT,
    const unsigned short* __restrict__ x0t, const float* __restrict__ x1,
    const float* __restrict__ gamma,
    float* __restrict__ out, float* __restrict__ li)
{
  const int lb = blockIdx.x;
  const int b    = (lb & 7) >> 1;                    // batch -> XCD pair
  const int mblk = ((lb >> 3) << 1) | (lb & 1);      // 0..127
  const int m0 = mblk * 32;
  const int tid = threadIdx.x;
  const int lane = tid & 63;
  const int wid = tid >> 6;                          // 0..7
  const int lr = lane & 15, lg = lane >> 4;
  const int mt = wid & 1, nq = wid >> 1;

  __shared__ __align__(16) unsigned short Abuf[2][TSZ_];   // 2 x 32KB, linear
  __shared__ __align__(16) unsigned short Plds[2][32 * 64];// 2 x 4KB, swizzled
  __shared__ float ssum[8][16];
  __shared__ float Sinv[32];

  const bf16x8 kf = *(const bf16x8*)(kT + ((size_t)b * W_ + m0 + mt * 16 + lr) * DQK_ + lg * 8);
  const unsigned short* qfw = qf + ((size_t)b * 256 * 64 + (size_t)nq * 64 + lane) * 8;
  const unsigned short* xtb = x0t + (size_t)b * NT64_ * TSZ_;
  const unsigned short* sbase = xtb + wid * 2048 + lane * 8;
  unsigned short* adst = &Abuf[0][wid * 2048];

  #define STAGEP(SRC, BUF) do {                                                   \
    _Pragma("unroll")                                                             \
    for (int k2 = 0; k2 < 4; ++k2){                                               \
      __builtin_amdgcn_global_load_lds(                                           \
        (const __attribute__((address_space(1))) unsigned int*)((SRC) + k2 * 512),\
        (__attribute__((address_space(3))) unsigned int*)(adst + (BUF) * TSZ_ + k2 * 512), \
        16, 0, 0);                                                                \
    }                                                                             \
  } while(0)

  STAGEP(sbase, 0);   // tile 0

  f32x4 acc[2][2];
  #pragma unroll
  for (int ct = 0; ct < 2; ++ct)
    #pragma unroll
    for (int m2 = 0; m2 < 2; ++m2) acc[ct][m2] = (f32x4){0.f,0.f,0.f,0.f};

  // loop-invariant DS offsets
  const int mlocP = mt * 16 + lr;
  const int pw_off = mlocP * 64
      + (((nq * 2 + (lg >> 1)) ^ (mlocP & 7)) << 3) + (lg & 1) * 4;
  int afo[2][2], pfo[2][2];
  #pragma unroll
  for (int ct = 0; ct < 2; ++ct){
    const int crow = wid * 32 + ct * 16 + lr;
    #pragma unroll
    for (int ks = 0; ks < 2; ++ks)
      afo[ct][ks] = crow * 64 + (((ks * 4 + lg) ^ (crow & 7)) << 3);
  }
  #pragma unroll
  for (int m2 = 0; m2 < 2; ++m2){
    const int prow = m2 * 16 + lr;
    #pragma unroll
    for (int ks = 0; ks < 2; ++ks)
      pfo[m2][ks] = prow * 64 + (((ks * 4 + lg) ^ (prow & 7)) << 3);
  }

  const unsigned short* qp = qfw + 2048;
  const unsigned short* srcp = sbase + TSZ_;
  float ps = 0.f;

  bf16x8 qv = *(const bf16x8*)qfw;
  for (int s = 0; s < NT64_; ++s){
    const int cur = s & 1;

    // energy quarter -> unnormalized P[cur]; accumulate S in f32
    f32x4 e = __builtin_amdgcn_mfma_f32_16x16x32_bf16(qv, kf, (f32x4){0.f,0.f,0.f,0.f}, 0, 0, 0);
    f32x4 p;
    #pragma unroll
    for (int r = 0; r < 4; ++r) p[r] = fexp2f(e[r]);
    ps += (p[0] + p[1]) + (p[2] + p[3]);
    uint2 pv; pv.x = cvtpk(p[0], p[1]); pv.y = cvtpk(p[2], p[3]);
    *(uint2*)(&Plds[cur][0] + pw_off) = pv;

    __syncthreads();   // drains STAGE(s) (loads only) + P[cur] visible

    qv = *(const bf16x8*)qp;
    qp = (s == NT64_ - 2) ? qfw : (qp + 2048);
    STAGEP(srcp, cur ^ 1);
    srcp = (s == NT64_ - 2) ? sbase : (srcp + TSZ_);

    // PV on unnormalized P
    const unsigned short* Ab = &Abuf[cur][0];
    const unsigned short* Pb = &Plds[cur][0];
    bf16x8 pf[2][2], af[2][2];
    __builtin_amdgcn_s_setprio(1);
    #pragma unroll
    for (int m2 = 0; m2 < 2; ++m2)
      #pragma unroll
      for (int ks = 0; ks < 2; ++ks)
        pf[m2][ks] = *(const bf16x8*)(Pb + pfo[m2][ks]);
    #pragma unroll
    for (int ct = 0; ct < 2; ++ct)
      #pragma unroll
      for (int ks = 0; ks < 2; ++ks)
        af[ct][ks] = *(const bf16x8*)(Ab + afo[ct][ks]);
    #pragma unroll
    for (int ct = 0; ct < 2; ++ct)
      #pragma unroll
      for (int m2 = 0; m2 < 2; ++m2){
        acc[ct][m2] = __builtin_amdgcn_mfma_f32_16x16x32_bf16(af[ct][0], pf[m2][0], acc[ct][m2], 0, 0, 0);
        acc[ct][m2] = __builtin_amdgcn_mfma_f32_16x16x32_bf16(af[ct][1], pf[m2][1], acc[ct][m2], 0, 0, 0);
      }
    __builtin_amdgcn_s_setprio(0);
  }
  #undef STAGEP

  // ---- denominators: cross-lane + cross-wave reduce ----
  ps += __shfl_xor(ps, 16);
  ps += __shfl_xor(ps, 32);
  if (lane < 16) ssum[wid][lane] = ps;
  __syncthreads();
  if (tid < 32){
    const int mtx = tid >> 4, l = tid & 15;
    const float S = ssum[mtx][l] + ssum[mtx + 2][l] + ssum[mtx + 4][l] + ssum[mtx + 6][l];
    Sinv[tid] = frcpf(S);
    li[(size_t)b * W_ + m0 + tid] = -log2f(S);   // for pass B
  }
  __syncthreads();

  // ---- epilogue: out[c][m] = gamma*invS[m]*acc + x1 ----
  const float g = gamma[0];
  const float gs0 = g * Sinv[lr];        // m2=0 column scale
  const float gs1 = g * Sinv[16 + lr];   // m2=1
  const float* x1b = x1 + (size_t)b * C_ * W_;
  float* outb = out + (size_t)b * C_ * W_;
  #pragma unroll
  for (int ct = 0; ct < 2; ++ct)
    #pragma unroll
    for (int m2 = 0; m2 < 2; ++m2){
      const float gs = m2 ? gs1 : gs0;
      #pragma unroll
      for (int r = 0; r < 4; ++r){
        const int c = wid * 32 + ct * 16 + lg * 4 + r;
        const size_t idx = (size_t)c * W_ + m0 + m2 * 16 + lr;
        const float xv = __builtin_nontemporal_load(&x1b[idx]);
        __builtin_nontemporal_store(fmaf(gs, acc[ct][m2][r], xv), &outb[idx]);
      }
    }
}

// ---------------------------------------------------------------------------
// K3 (pass B): pure attention writer. p = exp2(e + li[m]) -> normalized.
// No LDS, NO barriers, contiguous f32x4 NT stores -> write-roofline kernel.
// grid 512 (XCD-paired), block 512 = 8 waves, wave (nq, mt) as pass A.
// ---------------------------------------------------------------------------
__global__ __launch_bounds__(512) void sa_att(
    const unsigned short* __restrict__ qf, const unsigned short* __restrict__ kT,
    const float* __restrict__ li, float* __restrict__ att)
{
  const int lb = blockIdx.x;
  const int b    = (lb & 7) >> 1;
  const int mblk = ((lb >> 3) << 1) | (lb & 1);
  const int m0 = mblk * 32;
  const int lane = threadIdx.x & 63;
  const int wid = threadIdx.x >> 6;
  const int lr = lane & 15, lg = lane >> 4;
  const int mt = wid & 1, nq = wid >> 1;

  const bf16x8 kf = *(const bf16x8*)(kT + ((size_t)b * W_ + m0 + mt * 16 + lr) * DQK_ + lg * 8);
  const unsigned short* qfw = qf + ((size_t)b * 256 * 64 + (size_t)nq * 64 + lane) * 8;
  const float lival = li[(size_t)b * W_ + m0 + mt * 16 + lr];   // per-lane row shift

  float* attw = att + ((size_t)b * W_ + m0 + mt * 16 + lr) * W_ + nq * 16 + lg * 4;

  const unsigned short* qp = qfw + 2048;
  bf16x8 qv = *(const bf16x8*)qfw;
  for (int s = 0; s < NT64_; ++s){
    bf16x8 qn = *(const bf16x8*)qp;             // prefetch next tile
    qp = (s == NT64_ - 2) ? qfw : (qp + 2048);
    f32x4 e = __builtin_amdgcn_mfma_f32_16x16x32_bf16(qv, kf, (f32x4){0.f,0.f,0.f,0.f}, 0, 0, 0);
    f32x4 p;
    #pragma unroll
    for (int r = 0; r < 4; ++r) p[r] = fexp2f(e[r] + lival);
    __builtin_nontemporal_store(p, (f32x4*)attw);
    attw += 64;
    qv = qn;
  }
}

extern "C" void kernel_launch(void* const* d_in, const int* in_sizes, int n_in,
                              void* d_out, int out_size, void* d_ws, size_t ws_size,
                              hipStream_t stream)
{
  (void)in_sizes; (void)n_in; (void)out_size; (void)ws_size;
  const float* x0    = (const float*)d_in[0];
  const float* x1    = (const float*)d_in[1];
  const float* wq    = (const float*)d_in[2];
  const float* bq    = (const float*)d_in[3];
  const float* wk    = (const float*)d_in[4];
  const float* bk    = (const float*)d_in[5];
  const float* gamma = (const float*)d_in[6];

  unsigned short* qf  = (unsigned short*)d_ws;                   // 1 MB (fragment layout)
  unsigned short* kT  = qf + (size_t)B_ * W_ * DQK_;             // 1 MB
  unsigned short* x0t = kT + (size_t)B_ * W_ * DQK_;             // 8 MB swizzled tiles
  float*          li  = (float*)(x0t + (size_t)B_ * NT64_ * TSZ_); // 64 KB

  float* out = (float*)d_out;                                    // [B][C][W]
  float* att = out + (size_t)B_ * C_ * W_;                       // [B][W][W]

  sa_prep<<<dim3(128, 4), 512, 0, stream>>>(x0, x1, wq, bq, wk, bk, qf, kT, x0t);
  sa_pvd <<<512, 512, 0, stream>>>(qf, kT, x0t, x1, gamma, out, li);
  sa_att <<<512, 512, 0, stream>>>(qf, kT, li, att);
}

// Round 14
// 155.281 us; speedup vs baseline: 1.2986x; 1.2986x over previous
//
#include <hip/hip_runtime.h>
#include <stdint.h>

#define B_    4
#define C_    256
#define W_    4096
#define DQK_  32
#define NT64_ 64      // 64-wide n tiles per batch
#define TSZ_  16384   // shorts per x0f tile (8 wb x 4 frag x 64 lane x 8)

typedef short bf16x8 __attribute__((ext_vector_type(8)));
typedef float f32x4  __attribute__((ext_vector_type(4)));

__device__ __forceinline__ float fexp2f(float x){
#if __has_builtin(__builtin_amdgcn_exp2f)
  return __builtin_amdgcn_exp2f(x);
#else
  return exp2f(x);
#endif
}
__device__ __forceinline__ float frcpf(float x){
#if __has_builtin(__builtin_amdgcn_rcpf)
  return __builtin_amdgcn_rcpf(x);
#else
  return 1.0f / x;
#endif
}
// single-instruction packed f32->bf16 (RTNE)
__device__ __forceinline__ uint32_t cvtpk(float a, float b){
  uint32_t r;
  asm("v_cvt_pk_bf16_f32 %0, %1, %2" : "=v"(r) : "v"(a), "v"(b));
  return r;
}
__device__ __forceinline__ unsigned short bf16c(float f){
  return (unsigned short)cvtpk(f, f);
}

// ---------------------------------------------------------------------------
// K1: projections -> qf (MFMA-fragment layout) + kT (row-major) + x0 -> bf16
//     in PV-FRAGMENT layout x0f[b][n>>6][wb][ct*2+ks][lane][8]:
//     element (wb,ct,ks,lane=(lr,lg),j) = x0[c=wb*32+ct*16+lr][n=s*64+ks*32+lg*8+j]
//     so sa_fused's A-operands are 4 contiguous 1KB wave-loads -> VGPRs (no LDS).
// grid (128,4) block 512: block = 32 n x 256 c.
// ---------------------------------------------------------------------------
__global__ __launch_bounds__(512) void sa_prep(
    const float* __restrict__ x0, const float* __restrict__ x1,
    const float* __restrict__ wq, const float* __restrict__ bq,
    const float* __restrict__ wk, const float* __restrict__ bk,
    unsigned short* __restrict__ qf, unsigned short* __restrict__ kT,
    unsigned short* __restrict__ x0f)
{
  const int b     = blockIdx.y;
  const int tid   = threadIdx.x;
  const int lane  = tid & 63;
  const int cq    = tid >> 6;            // 0..7
  const int wloc  = lane & 31;           // n within the 32-block
  const int chalf = lane >> 5;           // 0..1
  const int n0    = blockIdx.x * 32;
  const int n     = n0 + wloc;
  const int c0    = cq * 32 + chalf * 16;
  const size_t bw = (size_t)b * ((size_t)C_ * W_) + n;

  __shared__ union {
    unsigned short xs[256 * 32];   // bf16 stage [c][nloc], 16 KB
    float red[8][32][36];          // cross-wave reduce, 36.9 KB
  } sm;

  float accq[DQK_], acck[DQK_];
  #pragma unroll
  for (int d = 0; d < DQK_; ++d){ accq[d] = 0.f; acck[d] = 0.f; }

  for (int i = 0; i < 16; ++i){
    const int c = c0 + i;
    const size_t off = bw + (size_t)c * W_;
    const float v0 = x0[off];
    const float v1 = x1[off];
    sm.xs[c * 32 + wloc] = bf16c(v0);
    #pragma unroll
    for (int d = 0; d < DQK_; ++d){
      accq[d] = fmaf(wq[d * C_ + c], v0, accq[d]);
      acck[d] = fmaf(wk[d * C_ + c], v1, acck[d]);
    }
  }
  #pragma unroll
  for (int d = 0; d < DQK_; ++d){
    accq[d] += __shfl_xor(accq[d], 32);
    acck[d] += __shfl_xor(acck[d], 32);
  }
  __syncthreads();   // xs complete

  // ---- flush x0f in PV-fragment order (coalesced 1KB per 64-lane group) ----
  {
    unsigned short* xt = x0f + (size_t)(b * NT64_ + (n0 >> 6)) * TSZ_;
    const int ks = (n0 >> 5) & 1;        // which K=32 half of the 64-n tile
    const int wb = tid >> 6;             // c-block 0..7
    const int lr2 = lane & 15, lg2 = lane >> 4;
    #pragma unroll
    for (int ct = 0; ct < 2; ++ct){
      uint4 v = *(const uint4*)&sm.xs[(wb * 32 + ct * 16 + lr2) * 32 + lg2 * 8];
      *(uint4*)(xt + ((size_t)(wb * 4 + ct * 2 + ks) * 64 + lane) * 8) = v;
    }
  }
  __syncthreads();   // xs free -> red may overwrite

  if (chalf == 0){
    #pragma unroll
    for (int d4 = 0; d4 < 8; ++d4){
      f32x4 t = { accq[d4*4], accq[d4*4+1], accq[d4*4+2], accq[d4*4+3] };
      *(f32x4*)&sm.red[cq][wloc][d4 * 4] = t;
    }
  }
  __syncthreads();
  if (tid < 256){
    const int nl = tid & 31, dg = tid >> 5;
    const int d0 = dg * 4;
    float s[4];
    #pragma unroll
    for (int j = 0; j < 4; ++j){
      float t = bq[d0 + j];
      #pragma unroll
      for (int g = 0; g < 8; ++g) t += sm.red[g][nl][d0 + j];
      s[j] = t;
    }
    uint2 pk; pk.x = cvtpk(s[0], s[1]); pk.y = cvtpk(s[2], s[3]);
    const int ng = n0 + nl;
    const size_t addr = (((size_t)b * 256 + (ng >> 4)) * 64
                         + (ng & 15) + ((dg >> 1) << 4)) * 8 + (dg & 1) * 4;
    *(uint2*)(qf + addr) = pk;
  }
  __syncthreads();

  if (chalf == 0){
    #pragma unroll
    for (int d4 = 0; d4 < 8; ++d4){
      f32x4 t = { acck[d4*4], acck[d4*4+1], acck[d4*4+2], acck[d4*4+3] };
      *(f32x4*)&sm.red[cq][wloc][d4 * 4] = t;
    }
  }
  __syncthreads();
  if (tid < 256){
    const float SCL = 0.0625f * 1.44269504088896340736f; // 1/sqrt(256)*log2(e)
    const int nl = tid & 31, dg = tid >> 5;
    const int d0 = dg * 4;
    float s[4];
    #pragma unroll
    for (int j = 0; j < 4; ++j){
      float t = bk[d0 + j];
      #pragma unroll
      for (int g = 0; g < 8; ++g) t += sm.red[g][nl][d0 + j];
      s[j] = t * SCL;
    }
    uint2 pk; pk.x = cvtpk(s[0], s[1]); pk.y = cvtpk(s[2], s[3]);
    *(uint2*)(kT + ((size_t)b * W_ + n0 + nl) * DQK_ + d0) = pk;
  }
}

// ---------------------------------------------------------------------------
// K2: fused denom + attention-write + PV + epilogue (R12 structure).
// R14: x0 fragments load DIRECT TO REGISTERS from x0f (no Abuf, no STAGE,
// no global_load_lds). LDS = P only (2x4KB double-buffer). The per-iter
// barrier needs NO vmcnt at all: pure lgkmcnt(0) + s_barrier (P visibility).
// qv(s+1) and af(s+1) register-prefetched; compiler counts their vmcnt.
// grid 512 (XCD-paired per batch), block 512 = 8 waves, 2 blocks/CU.
// ---------------------------------------------------------------------------
__global__ __launch_bounds__(512, 4) void sa_fused(
    const unsigned short* __restrict__ qf, const unsigned short* __restrict__ kT,
    const unsigned short* __restrict__ x0f, const float* __restrict__ x1,
    const float* __restrict__ gamma,
    float* __restrict__ out, float* __restrict__ att)
{
  const int lb = blockIdx.x;
  const int b    = (lb & 7) >> 1;                    // batch -> XCD pair
  const int mblk = ((lb >> 3) << 1) | (lb & 1);      // 0..127
  const int m0 = mblk * 32;
  const int tid = threadIdx.x;
  const int lane = tid & 63;
  const int wid = tid >> 6;                          // 0..7
  const int lr = lane & 15, lg = lane >> 4;
  const int mt = wid & 1, nq = wid >> 1;

  __shared__ __align__(16) unsigned short Plds[2][32 * 64]; // 2 x 4KB, swizzled
  __shared__ float ssum[8][16];

  const bf16x8 kf = *(const bf16x8*)(kT + ((size_t)b * W_ + m0 + mt * 16 + lr) * DQK_ + lg * 8);
  const unsigned short* qfw = qf + ((size_t)b * 256 * 64 + (size_t)nq * 64 + lane) * 8;
  const unsigned short* afw = x0f + (size_t)b * NT64_ * TSZ_ + wid * 2048 + lane * 8;

  // ---- pass 1: denominators (energy-only), q prefetched 1 iter ahead ----
  float ps = 0.f;
  {
    const unsigned short* qp = qfw + 2048;
    bf16x8 qv = *(const bf16x8*)qfw;
    for (int s = 0; s < NT64_; ++s){
      bf16x8 qn = *(const bf16x8*)qp;
      qp = (s == NT64_ - 2) ? qfw : (qp + 2048);
      f32x4 e = __builtin_amdgcn_mfma_f32_16x16x32_bf16(qv, kf, (f32x4){0.f,0.f,0.f,0.f}, 0, 0, 0);
      ps += fexp2f(e[0]) + fexp2f(e[1]) + fexp2f(e[2]) + fexp2f(e[3]);
      qv = qn;
    }
  }
  ps += __shfl_xor(ps, 16);
  ps += __shfl_xor(ps, 32);
  if (lane < 16) ssum[wid][lane] = ps;
  __syncthreads();
  const float is = frcpf(ssum[mt][lr] + ssum[mt + 2][lr] + ssum[mt + 4][lr] + ssum[mt + 6][lr]);

  // ---- pass 2 ----
  f32x4 acc[2][2];
  #pragma unroll
  for (int ct = 0; ct < 2; ++ct)
    #pragma unroll
    for (int m2 = 0; m2 < 2; ++m2) acc[ct][m2] = (f32x4){0.f,0.f,0.f,0.f};

  const int mlocP = mt * 16 + lr;
  const int pw_off = mlocP * 64
      + (((nq * 2 + (lg >> 1)) ^ (mlocP & 7)) << 3) + (lg & 1) * 4;
  int pfo[2][2];
  #pragma unroll
  for (int m2 = 0; m2 < 2; ++m2){
    const int prow = m2 * 16 + lr;
    #pragma unroll
    for (int ks = 0; ks < 2; ++ks)
      pfo[m2][ks] = prow * 64 + (((ks * 4 + lg) ^ (prow & 7)) << 3);
  }

  const unsigned short* qp = qfw + 2048;     // q tile for s+1
  const unsigned short* afp = afw + TSZ_;    // x0f tile for s+1
  float* attw = att + ((size_t)b * W_ + m0 + mt * 16 + lr) * W_ + nq * 16 + lg * 4;

  bf16x8 qv = *(const bf16x8*)qfw;           // q for s=0
  bf16x8 af0 = *(const bf16x8*)(afw);        // A-frags for s=0 (ct*2+ks order)
  bf16x8 af1 = *(const bf16x8*)(afw + 512);
  bf16x8 af2 = *(const bf16x8*)(afw + 1024);
  bf16x8 af3 = *(const bf16x8*)(afw + 1536);

  for (int s = 0; s < NT64_; ++s){
    const int cur = s & 1;

    // energy quarter -> P[cur]
    f32x4 e = __builtin_amdgcn_mfma_f32_16x16x32_bf16(qv, kf, (f32x4){0.f,0.f,0.f,0.f}, 0, 0, 0);
    f32x4 p;
    #pragma unroll
    for (int r = 0; r < 4; ++r) p[r] = fexp2f(e[r]) * is;
    uint2 pv; pv.x = cvtpk(p[0], p[1]); pv.y = cvtpk(p[2], p[3]);
    *(uint2*)(&Plds[cur][0] + pw_off) = pv;

    // pure-LDS barrier: P[cur] visible; NO vmcnt drain here
    asm volatile("s_waitcnt lgkmcnt(0)" ::: "memory");
    __builtin_amdgcn_sched_barrier(0);
    __builtin_amdgcn_s_barrier();

    // prefetch next-tile operands + store att(s)
    qv = *(const bf16x8*)qp;
    qp = (s == NT64_ - 2) ? qfw : (qp + 2048);
    bf16x8 an0 = *(const bf16x8*)(afp);
    bf16x8 an1 = *(const bf16x8*)(afp + 512);
    bf16x8 an2 = *(const bf16x8*)(afp + 1024);
    bf16x8 an3 = *(const bf16x8*)(afp + 1536);
    afp = (s == NT64_ - 2) ? afw : (afp + TSZ_);
    __builtin_nontemporal_store(p, (f32x4*)attw);
    attw += 64;

    // PV: A = x0 fragments (registers), B = P[cur] (swizzled LDS)
    const unsigned short* Pb = &Plds[cur][0];
    bf16x8 pf[2][2];
    __builtin_amdgcn_s_setprio(1);
    #pragma unroll
    for (int m2 = 0; m2 < 2; ++m2)
      #pragma unroll
      for (int ks = 0; ks < 2; ++ks)
        pf[m2][ks] = *(const bf16x8*)(Pb + pfo[m2][ks]);
    acc[0][0] = __builtin_amdgcn_mfma_f32_16x16x32_bf16(af0, pf[0][0], acc[0][0], 0, 0, 0);
    acc[0][1] = __builtin_amdgcn_mfma_f32_16x16x32_bf16(af0, pf[1][0], acc[0][1], 0, 0, 0);
    acc[0][0] = __builtin_amdgcn_mfma_f32_16x16x32_bf16(af1, pf[0][1], acc[0][0], 0, 0, 0);
    acc[0][1] = __builtin_amdgcn_mfma_f32_16x16x32_bf16(af1, pf[1][1], acc[0][1], 0, 0, 0);
    acc[1][0] = __builtin_amdgcn_mfma_f32_16x16x32_bf16(af2, pf[0][0], acc[1][0], 0, 0, 0);
    acc[1][1] = __builtin_amdgcn_mfma_f32_16x16x32_bf16(af2, pf[1][0], acc[1][1], 0, 0, 0);
    acc[1][0] = __builtin_amdgcn_mfma_f32_16x16x32_bf16(af3, pf[0][1], acc[1][0], 0, 0, 0);
    acc[1][1] = __builtin_amdgcn_mfma_f32_16x16x32_bf16(af3, pf[1][1], acc[1][1], 0, 0, 0);
    __builtin_amdgcn_s_setprio(0);

    af0 = an0; af1 = an1; af2 = an2; af3 = an3;
  }

  // ---- epilogue: out[c][m] = gamma*acc + x1 (nontemporal both ways) ----
  const float g = gamma[0];
  const float* x1b = x1 + (size_t)b * C_ * W_;
  float* outb = out + (size_t)b * C_ * W_;
  #pragma unroll
  for (int ct = 0; ct < 2; ++ct)
    #pragma unroll
    for (int m2 = 0; m2 < 2; ++m2)
      #pragma unroll
      for (int r = 0; r < 4; ++r){
        const int c = wid * 32 + ct * 16 + lg * 4 + r;
        const size_t idx = (size_t)c * W_ + m0 + m2 * 16 + lr;
        const float xv = __builtin_nontemporal_load(&x1b[idx]);
        __builtin_nontemporal_store(fmaf(g, acc[ct][m2][r], xv), &outb[idx]);
      }
}

extern "C" void kernel_launch(void* const* d_in, const int* in_sizes, int n_in,
                              void* d_out, int out_size, void* d_ws, size_t ws_size,
                              hipStream_t stream)
{
  (void)in_sizes; (void)n_in; (void)out_size; (void)ws_size;
  const float* x0    = (const float*)d_in[0];
  const float* x1    = (const float*)d_in[1];
  const float* wq    = (const float*)d_in[2];
  const float* bq    = (const float*)d_in[3];
  const float* wk    = (const float*)d_in[4];
  const float* bk    = (const float*)d_in[5];
  const float* gamma = (const float*)d_in[6];

  unsigned short* qf  = (unsigned short*)d_ws;                   // 1 MB (fragment layout)
  unsigned short* kT  = qf + (size_t)B_ * W_ * DQK_;             // 1 MB
  unsigned short* x0f = kT + (size_t)B_ * W_ * DQK_;             // 8 MB fragment tiles

  float* out = (float*)d_out;                                    // [B][C][W]
  float* att = out + (size_t)B_ * C_ * W_;                       // [B][W][W]

  sa_prep <<<dim3(128, 4), 512, 0, stream>>>(x0, x1, wq, bq, wk, bk, qf, kT, x0f);
  sa_fused<<<512, 512, 0, stream>>>(qf, kT, x0f, x1, gamma, out, att);
}

// Round 15
// 128.366 us; speedup vs baseline: 1.5709x; 1.2097x over previous
//
#include <hip/hip_runtime.h>
#include <stdint.h>

#define B_    4
#define C_    256
#define W_    4096
#define DQK_  32
#define NT64_ 64      // 64-wide n tiles per batch
#define TSZ_  16384   // shorts per x0f tile (8 wb x 4 frag x 64 lane x 8)

typedef short bf16x8 __attribute__((ext_vector_type(8)));
typedef float f32x4  __attribute__((ext_vector_type(4)));

__device__ __forceinline__ float fexp2f(float x){
#if __has_builtin(__builtin_amdgcn_exp2f)
  return __builtin_amdgcn_exp2f(x);
#else
  return exp2f(x);
#endif
}
__device__ __forceinline__ float frcpf(float x){
#if __has_builtin(__builtin_amdgcn_rcpf)
  return __builtin_amdgcn_rcpf(x);
#else
  return 1.0f / x;
#endif
}
// single-instruction packed f32->bf16 (RTNE)
__device__ __forceinline__ uint32_t cvtpk(float a, float b){
  uint32_t r;
  asm("v_cvt_pk_bf16_f32 %0, %1, %2" : "=v"(r) : "v"(a), "v"(b));
  return r;
}
__device__ __forceinline__ unsigned short bf16c(float f){
  return (unsigned short)cvtpk(f, f);
}

// ---------------------------------------------------------------------------
// K1 (R15 rewrite): block = 64 n x 256 c, 512 thr = 8 waves.
// lane = n-local (coalesced 256B x0/x1 reads); wave cq owns UNIFORM c-slice
// cq*32..+32 -> wq/wk indices wave-uniform -> scalar s_load broadcasts
// (R8-R14 had chalf-divergent c: every weight access was a per-lane VMEM
// gather, ~1GB redundant L2 traffic). x0 -> bf16 staged in LDS (pitch 68),
// flushed to PV-fragment layout x0f (intra-wave dep only). Projection
// partials reduced via pitch-33 f32 LDS (2-way banks max).
// grid (64,4).
// ---------------------------------------------------------------------------
__global__ __launch_bounds__(512) void sa_prep(
    const float* __restrict__ x0, const float* __restrict__ x1,
    const float* __restrict__ wq, const float* __restrict__ bq,
    const float* __restrict__ wk, const float* __restrict__ bk,
    unsigned short* __restrict__ qf, unsigned short* __restrict__ kT,
    unsigned short* __restrict__ x0f)
{
  const int b    = blockIdx.y;
  const int nt   = blockIdx.x;                 // 64-n tile index
  const int tid  = threadIdx.x;
  const int lane = tid & 63;
  const int cq   = __builtin_amdgcn_readfirstlane(tid >> 6);   // 0..7, uniform
  const int n    = nt * 64 + lane;
  const int lr   = lane & 15, lg = lane >> 4;
  const size_t bw = (size_t)b * ((size_t)C_ * W_) + n;

  __shared__ union {
    unsigned short xs[256 * 68];   // bf16 stage [c][n-local], pitch 68, 34.8KB
    float red[8][64][33];          // cross-wave reduce, 67.6KB
  } sm;

  float accq[DQK_], acck[DQK_];
  #pragma unroll
  for (int d = 0; d < DQK_; ++d){ accq[d] = 0.f; acck[d] = 0.f; }

  const int c0 = cq * 32;
  for (int i = 0; i < 32; ++i){
    const int c = c0 + i;                      // wave-uniform
    const size_t off = bw + (size_t)c * W_;
    const float v0 = x0[off];
    const float v1 = x1[off];
    sm.xs[c * 68 + lane] = bf16c(v0);
    #pragma unroll
    for (int d = 0; d < DQK_; ++d){
      accq[d] = fmaf(wq[d * C_ + c], v0, accq[d]);   // scalar loads (uniform)
      acck[d] = fmaf(wk[d * C_ + c], v1, acck[d]);
    }
  }

  // ---- flush x0f (intra-wave dependency only: rows are own c-slice) ----
  {
    unsigned short* xt = x0f + (size_t)(b * NT64_ + nt) * TSZ_;
    #pragma unroll
    for (int ct = 0; ct < 2; ++ct)
      #pragma unroll
      for (int ks = 0; ks < 2; ++ks){
        uint4 v = *(const uint4*)&sm.xs[(c0 + ct * 16 + lr) * 68 + ks * 32 + lg * 8];
        *(uint4*)(xt + ((size_t)((cq * 2 + ct) * 2 + ks) * 64 + lane) * 8) = v;
      }
  }
  __syncthreads();   // xs reads done -> red may overwrite

  // ---- q reduce + fragment-layout pack ----
  #pragma unroll
  for (int d = 0; d < DQK_; ++d) sm.red[cq][lane][d] = accq[d];
  __syncthreads();
  {
    const int nl = tid & 63, dg = tid >> 6;    // dg 0..7 -> d0 = dg*4
    const int d0 = dg * 4;
    float s[4];
    #pragma unroll
    for (int j = 0; j < 4; ++j){
      float t = bq[d0 + j];
      #pragma unroll
      for (int g = 0; g < 8; ++g) t += sm.red[g][nl][d0 + j];
      s[j] = t;
    }
    uint2 pk; pk.x = cvtpk(s[0], s[1]); pk.y = cvtpk(s[2], s[3]);
    const int ng = nt * 64 + nl;
    const size_t addr = (((size_t)b * 256 + (ng >> 4)) * 64
                         + (ng & 15) + ((dg >> 1) << 4)) * 8 + (dg & 1) * 4;
    *(uint2*)(qf + addr) = pk;
  }
  __syncthreads();

  // ---- k reduce + row-major pack (scaled) ----
  #pragma unroll
  for (int d = 0; d < DQK_; ++d) sm.red[cq][lane][d] = acck[d];
  __syncthreads();
  {
    const float SCL = 0.0625f * 1.44269504088896340736f; // 1/sqrt(256)*log2(e)
    const int nl = tid & 63, dg = tid >> 6;
    const int d0 = dg * 4;
    float s[4];
    #pragma unroll
    for (int j = 0; j < 4; ++j){
      float t = bk[d0 + j];
      #pragma unroll
      for (int g = 0; g < 8; ++g) t += sm.red[g][nl][d0 + j];
      s[j] = t * SCL;
    }
    uint2 pk; pk.x = cvtpk(s[0], s[1]); pk.y = cvtpk(s[2], s[3]);
    *(uint2*)(kT + ((size_t)b * W_ + nt * 64 + nl) * DQK_ + d0) = pk;
  }
}

// ---------------------------------------------------------------------------
// K2: fused denom + attention-write + PV + epilogue. BYTE-IDENTICAL to R14
// (x0 fragments direct-to-register, LDS = P only, pure-lgkmcnt barrier).
// grid 512 (XCD-paired per batch), block 512 = 8 waves, 2 blocks/CU.
// ---------------------------------------------------------------------------
__global__ __launch_bounds__(512, 4) void sa_fused(
    const unsigned short* __restrict__ qf, const unsigned short* __restrict__ kT,
    const unsigned short* __restrict__ x0f, const float* __restrict__ x1,
    const float* __restrict__ gamma,
    float* __restrict__ out, float* __restrict__ att)
{
  const int lb = blockIdx.x;
  const int b    = (lb & 7) >> 1;                    // batch -> XCD pair
  const int mblk = ((lb >> 3) << 1) | (lb & 1);      // 0..127
  const int m0 = mblk * 32;
  const int tid = threadIdx.x;
  const int lane = tid & 63;
  const int wid = tid >> 6;                          // 0..7
  const int lr = lane & 15, lg = lane >> 4;
  const int mt = wid & 1, nq = wid >> 1;

  __shared__ __align__(16) unsigned short Plds[2][32 * 64]; // 2 x 4KB, swizzled
  __shared__ float ssum[8][16];

  const bf16x8 kf = *(const bf16x8*)(kT + ((size_t)b * W_ + m0 + mt * 16 + lr) * DQK_ + lg * 8);
  const unsigned short* qfw = qf + ((size_t)b * 256 * 64 + (size_t)nq * 64 + lane) * 8;
  const unsigned short* afw = x0f + (size_t)b * NT64_ * TSZ_ + wid * 2048 + lane * 8;

  // ---- pass 1: denominators (energy-only), q prefetched 1 iter ahead ----
  float ps = 0.f;
  {
    const unsigned short* qp = qfw + 2048;
    bf16x8 qv = *(const bf16x8*)qfw;
    for (int s = 0; s < NT64_; ++s){
      bf16x8 qn = *(const bf16x8*)qp;
      qp = (s == NT64_ - 2) ? qfw : (qp + 2048);
      f32x4 e = __builtin_amdgcn_mfma_f32_16x16x32_bf16(qv, kf, (f32x4){0.f,0.f,0.f,0.f}, 0, 0, 0);
      ps += fexp2f(e[0]) + fexp2f(e[1]) + fexp2f(e[2]) + fexp2f(e[3]);
      qv = qn;
    }
  }
  ps += __shfl_xor(ps, 16);
  ps += __shfl_xor(ps, 32);
  if (lane < 16) ssum[wid][lane] = ps;
  __syncthreads();
  const float is = frcpf(ssum[mt][lr] + ssum[mt + 2][lr] + ssum[mt + 4][lr] + ssum[mt + 6][lr]);

  // ---- pass 2 ----
  f32x4 acc[2][2];
  #pragma unroll
  for (int ct = 0; ct < 2; ++ct)
    #pragma unroll
    for (int m2 = 0; m2 < 2; ++m2) acc[ct][m2] = (f32x4){0.f,0.f,0.f,0.f};

  const int mlocP = mt * 16 + lr;
  const int pw_off = mlocP * 64
      + (((nq * 2 + (lg >> 1)) ^ (mlocP & 7)) << 3) + (lg & 1) * 4;
  int pfo[2][2];
  #pragma unroll
  for (int m2 = 0; m2 < 2; ++m2){
    const int prow = m2 * 16 + lr;
    #pragma unroll
    for (int ks = 0; ks < 2; ++ks)
      pfo[m2][ks] = prow * 64 + (((ks * 4 + lg) ^ (prow & 7)) << 3);
  }

  const unsigned short* qp = qfw + 2048;     // q tile for s+1
  const unsigned short* afp = afw + TSZ_;    // x0f tile for s+1
  float* attw = att + ((size_t)b * W_ + m0 + mt * 16 + lr) * W_ + nq * 16 + lg * 4;

  bf16x8 qv = *(const bf16x8*)qfw;           // q for s=0
  bf16x8 af0 = *(const bf16x8*)(afw);        // A-frags for s=0 (ct*2+ks order)
  bf16x8 af1 = *(const bf16x8*)(afw + 512);
  bf16x8 af2 = *(const bf16x8*)(afw + 1024);
  bf16x8 af3 = *(const bf16x8*)(afw + 1536);

  for (int s = 0; s < NT64_; ++s){
    const int cur = s & 1;

    // energy quarter -> P[cur]
    f32x4 e = __builtin_amdgcn_mfma_f32_16x16x32_bf16(qv, kf, (f32x4){0.f,0.f,0.f,0.f}, 0, 0, 0);
    f32x4 p;
    #pragma unroll
    for (int r = 0; r < 4; ++r) p[r] = fexp2f(e[r]) * is;
    uint2 pv; pv.x = cvtpk(p[0], p[1]); pv.y = cvtpk(p[2], p[3]);
    *(uint2*)(&Plds[cur][0] + pw_off) = pv;

    // pure-LDS barrier: P[cur] visible; NO vmcnt drain here
    asm volatile("s_waitcnt lgkmcnt(0)" ::: "memory");
    __builtin_amdgcn_sched_barrier(0);
    __builtin_amdgcn_s_barrier();

    // prefetch next-tile operands + store att(s)
    qv = *(const bf16x8*)qp;
    qp = (s == NT64_ - 2) ? qfw : (qp + 2048);
    bf16x8 an0 = *(const bf16x8*)(afp);
    bf16x8 an1 = *(const bf16x8*)(afp + 512);
    bf16x8 an2 = *(const bf16x8*)(afp + 1024);
    bf16x8 an3 = *(const bf16x8*)(afp + 1536);
    afp = (s == NT64_ - 2) ? afw : (afp + TSZ_);
    __builtin_nontemporal_store(p, (f32x4*)attw);
    attw += 64;

    // PV: A = x0 fragments (registers), B = P[cur] (swizzled LDS)
    const unsigned short* Pb = &Plds[cur][0];
    bf16x8 pf[2][2];
    __builtin_amdgcn_s_setprio(1);
    #pragma unroll
    for (int m2 = 0; m2 < 2; ++m2)
      #pragma unroll
      for (int ks = 0; ks < 2; ++ks)
        pf[m2][ks] = *(const bf16x8*)(Pb + pfo[m2][ks]);
    acc[0][0] = __builtin_amdgcn_mfma_f32_16x16x32_bf16(af0, pf[0][0], acc[0][0], 0, 0, 0);
    acc[0][1] = __builtin_amdgcn_mfma_f32_16x16x32_bf16(af0, pf[1][0], acc[0][1], 0, 0, 0);
    acc[0][0] = __builtin_amdgcn_mfma_f32_16x16x32_bf16(af1, pf[0][1], acc[0][0], 0, 0, 0);
    acc[0][1] = __builtin_amdgcn_mfma_f32_16x16x32_bf16(af1, pf[1][1], acc[0][1], 0, 0, 0);
    acc[1][0] = __builtin_amdgcn_mfma_f32_16x16x32_bf16(af2, pf[0][0], acc[1][0], 0, 0, 0);
    acc[1][1] = __builtin_amdgcn_mfma_f32_16x16x32_bf16(af2, pf[1][0], acc[1][1], 0, 0, 0);
    acc[1][0] = __builtin_amdgcn_mfma_f32_16x16x32_bf16(af3, pf[0][1], acc[1][0], 0, 0, 0);
    acc[1][1] = __builtin_amdgcn_mfma_f32_16x16x32_bf16(af3, pf[1][1], acc[1][1], 0, 0, 0);
    __builtin_amdgcn_s_setprio(0);

    af0 = an0; af1 = an1; af2 = an2; af3 = an3;
  }

  // ---- epilogue: out[c][m] = gamma*acc + x1 (nontemporal both ways) ----
  const float g = gamma[0];
  const float* x1b = x1 + (size_t)b * C_ * W_;
  float* outb = out + (size_t)b * C_ * W_;
  #pragma unroll
  for (int ct = 0; ct < 2; ++ct)
    #pragma unroll
    for (int m2 = 0; m2 < 2; ++m2)
      #pragma unroll
      for (int r = 0; r < 4; ++r){
        const int c = wid * 32 + ct * 16 + lg * 4 + r;
        const size_t idx = (size_t)c * W_ + m0 + m2 * 16 + lr;
        const float xv = __builtin_nontemporal_load(&x1b[idx]);
        __builtin_nontemporal_store(fmaf(g, acc[ct][m2][r], xv), &outb[idx]);
      }
}

extern "C" void kernel_launch(void* const* d_in, const int* in_sizes, int n_in,
                              void* d_out, int out_size, void* d_ws, size_t ws_size,
                              hipStream_t stream)
{
  (void)in_sizes; (void)n_in; (void)out_size; (void)ws_size;
  const float* x0    = (const float*)d_in[0];
  const float* x1    = (const float*)d_in[1];
  const float* wq    = (const float*)d_in[2];
  const float* bq    = (const float*)d_in[3];
  const float* wk    = (const float*)d_in[4];
  const float* bk    = (const float*)d_in[5];
  const float* gamma = (const float*)d_in[6];

  unsigned short* qf  = (unsigned short*)d_ws;                   // 1 MB (fragment layout)
  unsigned short* kT  = qf + (size_t)B_ * W_ * DQK_;             // 1 MB
  unsigned short* x0f = kT + (size_t)B_ * W_ * DQK_;             // 8 MB fragment tiles

  float* out = (float*)d_out;                                    // [B][C][W]
  float* att = out + (size_t)B_ * C_ * W_;                       // [B][W][W]

  sa_prep <<<dim3(64, 4), 512, 0, stream>>>(x0, x1, wq, bq, wk, bk, qf, kT, x0f);
  sa_fused<<<512, 512, 0, stream>>>(qf, kT, x0f, x1, gamma, out, att);
}

// Round 16
// 126.907 us; speedup vs baseline: 1.5889x; 1.0115x over previous
//
#include <hip/hip_runtime.h>
#include <stdint.h>

#define B_    4
#define C_    256
#define W_    4096
#define DQK_  32
#define NT64_ 64      // 64-wide n tiles per batch
#define TSZ_  16384   // shorts per x0f tile (8 wb x 4 frag x 64 lane x 8)

typedef short bf16x8 __attribute__((ext_vector_type(8)));
typedef float f32x4  __attribute__((ext_vector_type(4)));

__device__ __forceinline__ float fexp2f(float x){
#if __has_builtin(__builtin_amdgcn_exp2f)
  return __builtin_amdgcn_exp2f(x);
#else
  return exp2f(x);
#endif
}
__device__ __forceinline__ float frcpf(float x){
#if __has_builtin(__builtin_amdgcn_rcpf)
  return __builtin_amdgcn_rcpf(x);
#else
  return 1.0f / x;
#endif
}
// single-instruction packed f32->bf16 (RTNE)
__device__ __forceinline__ uint32_t cvtpk(float a, float b){
  uint32_t r;
  asm("v_cvt_pk_bf16_f32 %0, %1, %2" : "=v"(r) : "v"(a), "v"(b));
  return r;
}
__device__ __forceinline__ unsigned short bf16c(float f){
  return (unsigned short)cvtpk(f, f);
}

// ---------------------------------------------------------------------------
// K1: UNCHANGED from R15 (wave-uniform weight c-slices -> scalar broadcasts).
// ---------------------------------------------------------------------------
__global__ __launch_bounds__(512) void sa_prep(
    const float* __restrict__ x0, const float* __restrict__ x1,
    const float* __restrict__ wq, const float* __restrict__ bq,
    const float* __restrict__ wk, const float* __restrict__ bk,
    unsigned short* __restrict__ qf, unsigned short* __restrict__ kT,
    unsigned short* __restrict__ x0f)
{
  const int b    = blockIdx.y;
  const int nt   = blockIdx.x;                 // 64-n tile index
  const int tid  = threadIdx.x;
  const int lane = tid & 63;
  const int cq   = __builtin_amdgcn_readfirstlane(tid >> 6);   // 0..7, uniform
  const int n    = nt * 64 + lane;
  const int lr   = lane & 15, lg = lane >> 4;
  const size_t bw = (size_t)b * ((size_t)C_ * W_) + n;

  __shared__ union {
    unsigned short xs[256 * 68];   // bf16 stage [c][n-local], pitch 68
    float red[8][64][33];          // cross-wave reduce
  } sm;

  float accq[DQK_], acck[DQK_];
  #pragma unroll
  for (int d = 0; d < DQK_; ++d){ accq[d] = 0.f; acck[d] = 0.f; }

  const int c0 = cq * 32;
  for (int i = 0; i < 32; ++i){
    const int c = c0 + i;                      // wave-uniform
    const size_t off = bw + (size_t)c * W_;
    const float v0 = x0[off];
    const float v1 = x1[off];
    sm.xs[c * 68 + lane] = bf16c(v0);
    #pragma unroll
    for (int d = 0; d < DQK_; ++d){
      accq[d] = fmaf(wq[d * C_ + c], v0, accq[d]);   // scalar loads (uniform)
      acck[d] = fmaf(wk[d * C_ + c], v1, acck[d]);
    }
  }

  // ---- flush x0f (intra-wave dependency only) ----
  {
    unsigned short* xt = x0f + (size_t)(b * NT64_ + nt) * TSZ_;
    #pragma unroll
    for (int ct = 0; ct < 2; ++ct)
      #pragma unroll
      for (int ks = 0; ks < 2; ++ks){
        uint4 v = *(const uint4*)&sm.xs[(c0 + ct * 16 + lr) * 68 + ks * 32 + lg * 8];
        *(uint4*)(xt + ((size_t)((cq * 2 + ct) * 2 + ks) * 64 + lane) * 8) = v;
      }
  }
  __syncthreads();   // xs reads done -> red may overwrite

  // ---- q reduce + fragment-layout pack ----
  #pragma unroll
  for (int d = 0; d < DQK_; ++d) sm.red[cq][lane][d] = accq[d];
  __syncthreads();
  {
    const int nl = tid & 63, dg = tid >> 6;
    const int d0 = dg * 4;
    float s[4];
    #pragma unroll
    for (int j = 0; j < 4; ++j){
      float t = bq[d0 + j];
      #pragma unroll
      for (int g = 0; g < 8; ++g) t += sm.red[g][nl][d0 + j];
      s[j] = t;
    }
    uint2 pk; pk.x = cvtpk(s[0], s[1]); pk.y = cvtpk(s[2], s[3]);
    const int ng = nt * 64 + nl;
    const size_t addr = (((size_t)b * 256 + (ng >> 4)) * 64
                         + (ng & 15) + ((dg >> 1) << 4)) * 8 + (dg & 1) * 4;
    *(uint2*)(qf + addr) = pk;
  }
  __syncthreads();

  // ---- k reduce + row-major pack (scaled) ----
  #pragma unroll
  for (int d = 0; d < DQK_; ++d) sm.red[cq][lane][d] = acck[d];
  __syncthreads();
  {
    const float SCL = 0.0625f * 1.44269504088896340736f; // 1/sqrt(256)*log2(e)
    const int nl = tid & 63, dg = tid >> 6;
    const int d0 = dg * 4;
    float s[4];
    #pragma unroll
    for (int j = 0; j < 4; ++j){
      float t = bk[d0 + j];
      #pragma unroll
      for (int g = 0; g < 8; ++g) t += sm.red[g][nl][d0 + j];
      s[j] = t * SCL;
    }
    uint2 pk; pk.x = cvtpk(s[0], s[1]); pk.y = cvtpk(s[2], s[3]);
    *(uint2*)(kT + ((size_t)b * W_ + nt * 64 + nl) * DQK_ + d0) = pk;
  }
}

// ---------------------------------------------------------------------------
// K2 (R16): m-tile 64 per block -> 256 blocks (1/CU), 8 waves = (nq 0..3,
// mh 0..1). Halves x0f/q L2 re-read traffic and barriers-per-output; doubles
// the loop body so the 1-iter-ahead prefetch covers L2 latency. Per wave/iter:
// 2 energy MFMA (shared qv) + 16 PV MFMA; af fragment loads unchanged (x0f
// layout identical). LDS: P 2x8KB double-buffer, pure-lgkmcnt barrier.
// ---------------------------------------------------------------------------
__global__ __launch_bounds__(512, 2) void sa_fused(
    const unsigned short* __restrict__ qf, const unsigned short* __restrict__ kT,
    const unsigned short* __restrict__ x0f, const float* __restrict__ x1,
    const float* __restrict__ gamma,
    float* __restrict__ out, float* __restrict__ att)
{
  const int lb = blockIdx.x;
  const int b    = (lb & 7) >> 1;                    // batch -> XCD pair
  const int mblk = ((lb >> 3) << 1) | (lb & 1);      // 0..63
  const int m0 = mblk * 64;
  const int tid = threadIdx.x;
  const int lane = tid & 63;
  const int wid = tid >> 6;                          // 0..7
  const int lr = lane & 15, lg = lane >> 4;
  const int nq = wid >> 1;                           // n-quarter 0..3
  const int mh = wid & 1;                            // m-half 0..1

  __shared__ __align__(16) unsigned short Plds[2][64 * 64]; // 2 x 8KB, swizzled
  __shared__ float ssum[4][64];

  const int row0 = mh * 32 + lr, row1 = row0 + 16;
  const bf16x8 kf0 = *(const bf16x8*)(kT + ((size_t)b * W_ + m0 + row0) * DQK_ + lg * 8);
  const bf16x8 kf1 = *(const bf16x8*)(kT + ((size_t)b * W_ + m0 + row1) * DQK_ + lg * 8);
  const unsigned short* qfw = qf + ((size_t)b * 256 * 64 + (size_t)nq * 64 + lane) * 8;
  const unsigned short* afw = x0f + (size_t)b * NT64_ * TSZ_ + wid * 2048 + lane * 8;

  // ---- pass 1: denominators (energy-only), q prefetched 1 iter ahead ----
  float ps0 = 0.f, ps1 = 0.f;
  {
    const unsigned short* qp = qfw + 2048;
    bf16x8 qv = *(const bf16x8*)qfw;
    for (int s = 0; s < NT64_; ++s){
      bf16x8 qn = *(const bf16x8*)qp;
      qp = (s == NT64_ - 2) ? qfw : (qp + 2048);
      f32x4 e0 = __builtin_amdgcn_mfma_f32_16x16x32_bf16(qv, kf0, (f32x4){0.f,0.f,0.f,0.f}, 0, 0, 0);
      f32x4 e1 = __builtin_amdgcn_mfma_f32_16x16x32_bf16(qv, kf1, (f32x4){0.f,0.f,0.f,0.f}, 0, 0, 0);
      ps0 += (fexp2f(e0[0]) + fexp2f(e0[1])) + (fexp2f(e0[2]) + fexp2f(e0[3]));
      ps1 += (fexp2f(e1[0]) + fexp2f(e1[1])) + (fexp2f(e1[2]) + fexp2f(e1[3]));
      qv = qn;
    }
  }
  ps0 += __shfl_xor(ps0, 16); ps0 += __shfl_xor(ps0, 32);
  ps1 += __shfl_xor(ps1, 16); ps1 += __shfl_xor(ps1, 32);
  if (lane < 16){
    ssum[nq][mh * 32 + lane]      = ps0;
    ssum[nq][mh * 32 + 16 + lane] = ps1;
  }
  __syncthreads();
  const float is0 = frcpf(ssum[0][row0] + ssum[1][row0] + ssum[2][row0] + ssum[3][row0]);
  const float is1 = frcpf(ssum[0][row1] + ssum[1][row1] + ssum[2][row1] + ssum[3][row1]);

  // ---- pass 2 ----
  f32x4 acc[2][4];
  #pragma unroll
  for (int ct = 0; ct < 2; ++ct)
    #pragma unroll
    for (int m2 = 0; m2 < 4; ++m2) acc[ct][m2] = (f32x4){0.f,0.f,0.f,0.f};

  const int pw0 = row0 * 64 + (((nq * 2 + (lg >> 1)) ^ (row0 & 7)) << 3) + (lg & 1) * 4;
  const int pw1 = row1 * 64 + (((nq * 2 + (lg >> 1)) ^ (row1 & 7)) << 3) + (lg & 1) * 4;
  int pfo[4][2];
  #pragma unroll
  for (int m2 = 0; m2 < 4; ++m2){
    const int prow = m2 * 16 + lr;
    #pragma unroll
    for (int ks = 0; ks < 2; ++ks)
      pfo[m2][ks] = prow * 64 + (((ks * 4 + lg) ^ (prow & 7)) << 3);
  }

  const unsigned short* qp = qfw + 2048;     // q tile for s+1
  const unsigned short* afp = afw + TSZ_;    // x0f tile for s+1
  float* attw0 = att + ((size_t)b * W_ + m0 + row0) * W_ + nq * 16 + lg * 4;
  float* attw1 = attw0 + (size_t)16 * W_;

  bf16x8 qv = *(const bf16x8*)qfw;           // q for s=0
  bf16x8 af0 = *(const bf16x8*)(afw);        // A-frags for s=0 (ct*2+ks order)
  bf16x8 af1 = *(const bf16x8*)(afw + 512);
  bf16x8 af2 = *(const bf16x8*)(afw + 1024);
  bf16x8 af3 = *(const bf16x8*)(afw + 1536);

  for (int s = 0; s < NT64_; ++s){
    const int cur = s & 1;

    // energy (2 quarters, shared qv) -> P[cur]
    f32x4 e0 = __builtin_amdgcn_mfma_f32_16x16x32_bf16(qv, kf0, (f32x4){0.f,0.f,0.f,0.f}, 0, 0, 0);
    f32x4 e1 = __builtin_amdgcn_mfma_f32_16x16x32_bf16(qv, kf1, (f32x4){0.f,0.f,0.f,0.f}, 0, 0, 0);
    f32x4 p0, p1;
    #pragma unroll
    for (int r = 0; r < 4; ++r){
      p0[r] = fexp2f(e0[r]) * is0;
      p1[r] = fexp2f(e1[r]) * is1;
    }
    uint2 pv0; pv0.x = cvtpk(p0[0], p0[1]); pv0.y = cvtpk(p0[2], p0[3]);
    uint2 pv1; pv1.x = cvtpk(p1[0], p1[1]); pv1.y = cvtpk(p1[2], p1[3]);
    *(uint2*)(&Plds[cur][0] + pw0) = pv0;
    *(uint2*)(&Plds[cur][0] + pw1) = pv1;

    // pure-LDS barrier: P[cur] visible; NO vmcnt drain
    asm volatile("s_waitcnt lgkmcnt(0)" ::: "memory");
    __builtin_amdgcn_sched_barrier(0);
    __builtin_amdgcn_s_barrier();

    // prefetch next-tile operands + store att(s)
    qv = *(const bf16x8*)qp;
    qp = (s == NT64_ - 2) ? qfw : (qp + 2048);
    bf16x8 an0 = *(const bf16x8*)(afp);
    bf16x8 an1 = *(const bf16x8*)(afp + 512);
    bf16x8 an2 = *(const bf16x8*)(afp + 1024);
    bf16x8 an3 = *(const bf16x8*)(afp + 1536);
    afp = (s == NT64_ - 2) ? afw : (afp + TSZ_);
    __builtin_nontemporal_store(p0, (f32x4*)attw0);
    __builtin_nontemporal_store(p1, (f32x4*)attw1);
    attw0 += 64; attw1 += 64;

    // PV: A = x0 fragments (registers), B = P[cur] (swizzled LDS)
    const unsigned short* Pb = &Plds[cur][0];
    bf16x8 pf[4][2];
    __builtin_amdgcn_s_setprio(1);
    #pragma unroll
    for (int m2 = 0; m2 < 4; ++m2)
      #pragma unroll
      for (int ks = 0; ks < 2; ++ks)
        pf[m2][ks] = *(const bf16x8*)(Pb + pfo[m2][ks]);
    #pragma unroll
    for (int m2 = 0; m2 < 4; ++m2){
      acc[0][m2] = __builtin_amdgcn_mfma_f32_16x16x32_bf16(af0, pf[m2][0], acc[0][m2], 0, 0, 0);
      acc[0][m2] = __builtin_amdgcn_mfma_f32_16x16x32_bf16(af1, pf[m2][1], acc[0][m2], 0, 0, 0);
      acc[1][m2] = __builtin_amdgcn_mfma_f32_16x16x32_bf16(af2, pf[m2][0], acc[1][m2], 0, 0, 0);
      acc[1][m2] = __builtin_amdgcn_mfma_f32_16x16x32_bf16(af3, pf[m2][1], acc[1][m2], 0, 0, 0);
    }
    __builtin_amdgcn_s_setprio(0);

    af0 = an0; af1 = an1; af2 = an2; af3 = an3;
  }

  // ---- epilogue: out[c][m] = gamma*acc + x1 (nontemporal both ways) ----
  const float g = gamma[0];
  const float* x1b = x1 + (size_t)b * C_ * W_;
  float* outb = out + (size_t)b * C_ * W_;
  #pragma unroll
  for (int ct = 0; ct < 2; ++ct)
    #pragma unroll
    for (int m2 = 0; m2 < 4; ++m2)
      #pragma unroll
      for (int r = 0; r < 4; ++r){
        const int c = wid * 32 + ct * 16 + lg * 4 + r;
        const size_t idx = (size_t)c * W_ + m0 + m2 * 16 + lr;
        const float xv = __builtin_nontemporal_load(&x1b[idx]);
        __builtin_nontemporal_store(fmaf(g, acc[ct][m2][r], xv), &outb[idx]);
      }
}

extern "C" void kernel_launch(void* const* d_in, const int* in_sizes, int n_in,
                              void* d_out, int out_size, void* d_ws, size_t ws_size,
                              hipStream_t stream)
{
  (void)in_sizes; (void)n_in; (void)out_size; (void)ws_size;
  const float* x0    = (const float*)d_in[0];
  const float* x1    = (const float*)d_in[1];
  const float* wq    = (const float*)d_in[2];
  const float* bq    = (const float*)d_in[3];
  const float* wk    = (const float*)d_in[4];
  const float* bk    = (const float*)d_in[5];
  const float* gamma = (const float*)d_in[6];

  unsigned short* qf  = (unsigned short*)d_ws;                   // 1 MB (fragment layout)
  unsigned short* kT  = qf + (size_t)B_ * W_ * DQK_;             // 1 MB
  unsigned short* x0f = kT + (size_t)B_ * W_ * DQK_;             // 8 MB fragment tiles

  float* out = (float*)d_out;                                    // [B][C][W]
  float* att = out + (size_t)B_ * C_ * W_;                       // [B][W][W]

  sa_prep <<<dim3(64, 4), 512, 0, stream>>>(x0, x1, wq, bq, wk, bk, qf, kT, x0f);
  sa_fused<<<256, 512, 0, stream>>>(qf, kT, x0f, x1, gamma, out, att);
}